// Round 1
// baseline (353.707 us; speedup 1.0000x reference)
//
#include <hip/hip_runtime.h>
#include <hip/hip_bf16.h>
#include <math.h>

// GNNAngle: per node, 16 neighbor vectors (D=32) -> normalize -> 120 pairwise
// angles -> MLP 120->128->128->128->1 (tanh,tanh,tanh,sigmoid).
// f32 baseline: VALU-bound (~123us MLP floor), HBM floor ~65us.

#define STRIDE 129   // LDS row stride (f32): (n*129+i)%32 == (n+i)%32 -> conflict-free
#define CHUNK  64    // nodes per block
#define NTHREADS 512 // 8 waves

__device__ __forceinline__ float fast_tanh(float x) {
    // tanh(x) = 1 - 2/(exp(2x)+1); handles +/-inf saturation correctly
    float e = __expf(2.0f * x);
    return 1.0f - 2.0f / (e + 1.0f);
}

template<int IN>
__device__ __forceinline__ void mlp_layer(const float* __restrict__ Wg,  // [IN][128] row-major
                                          const float* __restrict__ bg,  // [128]
                                          const float* src, float* dst,  // LDS, stride 129
                                          int n, int j0)
{
    float acc[16];
    {
        const float4* bp = (const float4*)(bg + j0);   // uniform -> s_load
        #pragma unroll
        for (int v = 0; v < 4; ++v) {
            float4 bv = bp[v];
            acc[v*4+0] = bv.x; acc[v*4+1] = bv.y; acc[v*4+2] = bv.z; acc[v*4+3] = bv.w;
        }
    }
    const float* s = src + n * STRIDE;
    #pragma unroll 4
    for (int i = 0; i < IN; ++i) {
        float a = s[i];                                 // per-lane LDS, conflict-free
        const float4* wr = (const float4*)(Wg + i * 128 + j0);  // uniform -> s_load
        float4 w0 = wr[0], w1 = wr[1], w2 = wr[2], w3 = wr[3];
        acc[0]  = fmaf(a, w0.x, acc[0]);
        acc[1]  = fmaf(a, w0.y, acc[1]);
        acc[2]  = fmaf(a, w0.z, acc[2]);
        acc[3]  = fmaf(a, w0.w, acc[3]);
        acc[4]  = fmaf(a, w1.x, acc[4]);
        acc[5]  = fmaf(a, w1.y, acc[5]);
        acc[6]  = fmaf(a, w1.z, acc[6]);
        acc[7]  = fmaf(a, w1.w, acc[7]);
        acc[8]  = fmaf(a, w2.x, acc[8]);
        acc[9]  = fmaf(a, w2.y, acc[9]);
        acc[10] = fmaf(a, w2.z, acc[10]);
        acc[11] = fmaf(a, w2.w, acc[11]);
        acc[12] = fmaf(a, w3.x, acc[12]);
        acc[13] = fmaf(a, w3.y, acc[13]);
        acc[14] = fmaf(a, w3.z, acc[14]);
        acc[15] = fmaf(a, w3.w, acc[15]);
    }
    float* d = dst + n * STRIDE + j0;
    #pragma unroll
    for (int jj = 0; jj < 16; ++jj)
        d[jj] = fast_tanh(acc[jj]);
}

__global__ __launch_bounds__(NTHREADS, 4)
void gnn_angle_fused(const float* __restrict__ edge_attr,
                     const float* __restrict__ W1, const float* __restrict__ b1,
                     const float* __restrict__ W2, const float* __restrict__ b2,
                     const float* __restrict__ W3, const float* __restrict__ b3,
                     const float* __restrict__ W4, const float* __restrict__ b4,
                     float* __restrict__ out, int n_nodes)
{
    __shared__ __attribute__((aligned(16))) float bufA[CHUNK * STRIDE]; // feats / acts ping
    __shared__ __attribute__((aligned(16))) float bufB[CHUNK * STRIDE]; // vecs (A) / acts pong

    const int t   = threadIdx.x;
    const int w   = t >> 6;   // wave 0..7
    const int l   = t & 63;   // lane
    const int base = blockIdx.x * CHUNK;

    // pair -> (i,j) mapping, computed once (same for every node)
    int i1, j1, i2 = 0, j2 = 0;
    {
        int p = l, i = 0;
        while (p >= 15 - i) { p -= 15 - i; ++i; }
        i1 = i; j1 = i + 1 + p;
    }
    const bool has2 = (l < 56);   // pairs l+64 valid while l+64 < 120
    if (has2) {
        int p = l + 64, i = 0;
        while (p >= 15 - i) { p -= 15 - i; ++i; }
        i2 = i; j2 = i + 1 + p;
    }

    // ---------------- Phase A: normalize + pairwise angles ----------------
    const int r = l >> 2;            // row 0..15
    const int q = l & 3;             // quarter of the 32-dim vector
    float* vw = bufB + w * 576;      // per-wave [16][36] f32 region (conflict-free pads)

    for (int it = 0; it < 8; ++it) {
        __syncthreads();                         // protect vecs reuse across iters
        const int m = it * 8 + w;                // local node 0..63
        const long g = (long)base + m;
        const bool valid = (g < n_nodes);
        float4 v0 = make_float4(0.f, 0.f, 0.f, 0.f);
        float4 v1 = v0;
        if (valid) {
            const float* src = edge_attr + g * 512 + r * 32 + q * 8;
            v0 = *(const float4*)(src);
            v1 = *(const float4*)(src + 4);
        }
        float ss = v0.x*v0.x + v0.y*v0.y + v0.z*v0.z + v0.w*v0.w
                 + v1.x*v1.x + v1.y*v1.y + v1.z*v1.z + v1.w*v1.w;
        ss += __shfl_xor(ss, 1);
        ss += __shfl_xor(ss, 2);                 // sum over the 4 quarter-lanes of row r
        const float sc = 1.0f / (sqrtf(ss) + 1e-12f);
        v0.x*=sc; v0.y*=sc; v0.z*=sc; v0.w*=sc;
        v1.x*=sc; v1.y*=sc; v1.z*=sc; v1.w*=sc;
        *(float4*)(vw + r*36 + q*8)     = v0;
        *(float4*)(vw + r*36 + q*8 + 4) = v1;
        __syncthreads();                         // vecs visible to whole wave
        {
            const float* va = vw + i1 * 36;
            const float* vb = vw + j1 * 36;
            float d = 0.f;
            #pragma unroll
            for (int c = 0; c < 8; ++c) {
                float4 a = *(const float4*)(va + c*4);
                float4 b = *(const float4*)(vb + c*4);
                d = fmaf(a.x, b.x, d); d = fmaf(a.y, b.y, d);
                d = fmaf(a.z, b.z, d); d = fmaf(a.w, b.w, d);
            }
            d = fminf(fmaxf(d, -1.0f + 1e-7f), 1.0f - 1e-7f);
            bufA[m * STRIDE + l] = acosf(d);
        }
        if (has2) {
            const float* va = vw + i2 * 36;
            const float* vb = vw + j2 * 36;
            float d = 0.f;
            #pragma unroll
            for (int c = 0; c < 8; ++c) {
                float4 a = *(const float4*)(va + c*4);
                float4 b = *(const float4*)(vb + c*4);
                d = fmaf(a.x, b.x, d); d = fmaf(a.y, b.y, d);
                d = fmaf(a.z, b.z, d); d = fmaf(a.w, b.w, d);
            }
            d = fminf(fmaxf(d, -1.0f + 1e-7f), 1.0f - 1e-7f);
            bufA[m * STRIDE + l + 64] = acosf(d);
        }
    }
    __syncthreads();   // feats complete for all 64 nodes

    // ---------------- Phase B: MLP ----------------
    // lane = node (n = l); each wave computes a wave-uniform 16-wide j-slice,
    // so weight/bias loads are scalar (SMEM) broadcasts shared by 64 nodes.
    const int n  = l;
    const int j0 = __builtin_amdgcn_readfirstlane(w) * 16;

    mlp_layer<120>(W1, b1, bufA, bufB, n, j0);   // feats(120) -> h1
    __syncthreads();
    mlp_layer<128>(W2, b2, bufB, bufA, n, j0);   // h1 -> h2
    __syncthreads();
    mlp_layer<128>(W3, b3, bufA, bufB, n, j0);   // h2 -> h3
    __syncthreads();

    if (j0 == 0) {                               // wave 0: final 128->1 + sigmoid
        float a = b4[0];
        const float* s = bufB + n * STRIDE;
        #pragma unroll 8
        for (int i = 0; i < 128; ++i)
            a = fmaf(s[i], W4[i], a);            // W4[i] uniform -> s_load
        const long g = (long)base + n;
        if (g < n_nodes)
            out[g] = 1.0f / (1.0f + __expf(-a));
    }
}

extern "C" void kernel_launch(void* const* d_in, const int* in_sizes, int n_in,
                              void* d_out, int out_size, void* d_ws, size_t ws_size,
                              hipStream_t stream) {
    // inputs: 0:x 1:edge_index 2:edge_attr 3:k 4:W1 5:b1 6:W2 7:b2 8:W3 9:b3 10:W4 11:b4
    const float* edge_attr = (const float*)d_in[2];
    const float* W1 = (const float*)d_in[4];
    const float* b1 = (const float*)d_in[5];
    const float* W2 = (const float*)d_in[6];
    const float* b2 = (const float*)d_in[7];
    const float* W3 = (const float*)d_in[8];
    const float* b3 = (const float*)d_in[9];
    const float* W4 = (const float*)d_in[10];
    const float* b4 = (const float*)d_in[11];
    float* out = (float*)d_out;

    const int n_nodes = in_sizes[2] / 512;       // E*D / (16*32)
    const int blocks = (n_nodes + CHUNK - 1) / CHUNK;

    gnn_angle_fused<<<blocks, NTHREADS, 0, stream>>>(
        edge_attr, W1, b1, W2, b2, W3, b3, W4, b4, out, n_nodes);
}

// Round 2
// 177.176 us; speedup vs baseline: 1.9964x; 1.9964x over previous
//
#include <hip/hip_runtime.h>
#include <hip/hip_bf16.h>
#include <math.h>

// GNNAngle: per node, 16 neighbor vectors (D=32) -> normalize -> 120 pairwise
// angles -> MLP 120->128->128->128->1 (tanh,tanh,tanh,sigmoid).
// Round 2: MLP on f16 MFMA (16x16x32), phase A stays f32 VALU.

#define CHUNK     64    // nodes per block
#define NTHREADS  512   // 8 waves
#define ASTRIDE   136   // f16 act row stride: (node*272+..)/4 banks spread, b128 conflict-free

typedef _Float16 f16;
typedef f16  f16x8 __attribute__((ext_vector_type(8)));
typedef f16  f16x4 __attribute__((ext_vector_type(4)));
typedef float f32x4 __attribute__((ext_vector_type(4)));

__device__ __forceinline__ float fast_tanh(float x) {
    float e = __expf(2.0f * x);
    return 1.0f - 2.0f / (e + 1.0f);
}

// ---- prep: W[i][j] (f32, row-major [IN][128]) -> Wt[j][i] f16 [128][128], K zero-padded
__global__ void prep_weights(const float* __restrict__ W1,
                             const float* __restrict__ W2,
                             const float* __restrict__ W3,
                             f16* __restrict__ wt)
{
    int tid = blockIdx.x * 256 + threadIdx.x;
    if (tid >= 3 * 128 * 128) return;
    int layer = tid >> 14;
    int rem   = tid & 16383;
    int j     = rem >> 7;
    int i     = rem & 127;
    const float* W = (layer == 0) ? W1 : ((layer == 1) ? W2 : W3);
    int in_l = (layer == 0) ? 120 : 128;
    float v = (i < in_l) ? W[i * 128 + j] : 0.0f;
    wt[tid] = (f16)v;   // wt[layer][j][i]
}

// one MLP layer on MFMA: dst[node][j] = tanh(sum_i src[node][i]*W[i][j] + b[j])
// wave decomposition: jg = wave>>1 (owns j-tiles 2jg,2jg+1), ng = wave&1 (node halves)
__device__ __forceinline__ void mlp_layer_mfma(const f16* __restrict__ wl,   // [128][128] f16 (global, [j][i])
                                               const float* __restrict__ bias,
                                               const f16* src, f16* dst,     // LDS, stride ASTRIDE
                                               int jg, int ng, int lr, int lg)
{
    f16x8 a0[4], a1[4];
    f32x4 bv0, bv1;
    {
        const int jt0 = jg * 2, jt1 = jg * 2 + 1;
        const f16* wr0 = wl + (jt0 * 16 + lr) * 128 + lg * 8;
        const f16* wr1 = wl + (jt1 * 16 + lr) * 128 + lg * 8;
        #pragma unroll
        for (int kt = 0; kt < 4; ++kt) {
            a0[kt] = *(const f16x8*)(wr0 + kt * 32);
            a1[kt] = *(const f16x8*)(wr1 + kt * 32);
        }
        bv0 = *(const f32x4*)(bias + jt0 * 16 + lg * 4);
        bv1 = *(const f32x4*)(bias + jt1 * 16 + lg * 4);
    }
    #pragma unroll
    for (int nt2 = 0; nt2 < 2; ++nt2) {
        const int node = (ng * 2 + nt2) * 16 + lr;
        const f16* sr = src + node * ASTRIDE + lg * 8;
        f16x8 bf0 = *(const f16x8*)(sr);
        f16x8 bf1 = *(const f16x8*)(sr + 32);
        f16x8 bf2 = *(const f16x8*)(sr + 64);
        f16x8 bf3 = *(const f16x8*)(sr + 96);
        f32x4 acc0 = {0.f, 0.f, 0.f, 0.f};
        f32x4 acc1 = {0.f, 0.f, 0.f, 0.f};
        acc0 = __builtin_amdgcn_mfma_f32_16x16x32_f16(a0[0], bf0, acc0, 0, 0, 0);
        acc1 = __builtin_amdgcn_mfma_f32_16x16x32_f16(a1[0], bf0, acc1, 0, 0, 0);
        acc0 = __builtin_amdgcn_mfma_f32_16x16x32_f16(a0[1], bf1, acc0, 0, 0, 0);
        acc1 = __builtin_amdgcn_mfma_f32_16x16x32_f16(a1[1], bf1, acc1, 0, 0, 0);
        acc0 = __builtin_amdgcn_mfma_f32_16x16x32_f16(a0[2], bf2, acc0, 0, 0, 0);
        acc1 = __builtin_amdgcn_mfma_f32_16x16x32_f16(a1[2], bf2, acc1, 0, 0, 0);
        acc0 = __builtin_amdgcn_mfma_f32_16x16x32_f16(a0[3], bf3, acc0, 0, 0, 0);
        acc1 = __builtin_amdgcn_mfma_f32_16x16x32_f16(a1[3], bf3, acc1, 0, 0, 0);
        // epilogue: D[row=j_local=lg*4+r][col=node=lr]; bias+tanh -> f16 -> LDS
        f16x4 o0, o1;
        #pragma unroll
        for (int r = 0; r < 4; ++r) {
            o0[r] = (f16)fast_tanh(acc0[r] + bv0[r]);
            o1[r] = (f16)fast_tanh(acc1[r] + bv1[r]);
        }
        *(f16x4*)(dst + node * ASTRIDE + (jg * 2 + 0) * 16 + lg * 4) = o0;
        *(f16x4*)(dst + node * ASTRIDE + (jg * 2 + 1) * 16 + lg * 4) = o1;
    }
}

__global__ __launch_bounds__(NTHREADS, 4)
void gnn_angle_fused(const float* __restrict__ edge_attr,
                     const f16*   __restrict__ wt,     // 3x[128][128] f16
                     const float* __restrict__ b1, const float* __restrict__ b2,
                     const float* __restrict__ b3,
                     const float* __restrict__ W4, const float* __restrict__ b4,
                     float* __restrict__ out, int n_nodes)
{
    __shared__ __attribute__((aligned(16))) f16   actA[CHUNK * ASTRIDE];
    __shared__ __attribute__((aligned(16))) f16   actB[CHUNK * ASTRIDE];
    __shared__ __attribute__((aligned(16))) float vecs[8 * 16 * 36];   // per-wave [16][36]

    const int t = threadIdx.x;
    const int w = t >> 6;
    const int l = t & 63;
    const int base = blockIdx.x * CHUNK;

    // pair -> (i,j) mapping (same for every node)
    int i1, j1, i2 = 0, j2 = 0;
    {
        int p = l, i = 0;
        while (p >= 15 - i) { p -= 15 - i; ++i; }
        i1 = i; j1 = i + 1 + p;
    }
    const bool has2 = (l < 56);
    if (has2) {
        int p = l + 64, i = 0;
        while (p >= 15 - i) { p -= 15 - i; ++i; }
        i2 = i; j2 = i + 1 + p;
    }

    // ---------------- Phase A: normalize + pairwise angles (f32) ----------------
    const int r = l >> 2;
    const int q = l & 3;
    float* vw = vecs + w * 576;

    for (int it = 0; it < 8; ++it) {
        __syncthreads();
        const int m = it * 8 + w;
        const long g = (long)base + m;
        const bool valid = (g < n_nodes);
        float4 v0 = make_float4(0.f, 0.f, 0.f, 0.f);
        float4 v1 = v0;
        if (valid) {
            const float* src = edge_attr + g * 512 + r * 32 + q * 8;
            v0 = *(const float4*)(src);
            v1 = *(const float4*)(src + 4);
        }
        float ss = v0.x*v0.x + v0.y*v0.y + v0.z*v0.z + v0.w*v0.w
                 + v1.x*v1.x + v1.y*v1.y + v1.z*v1.z + v1.w*v1.w;
        ss += __shfl_xor(ss, 1);
        ss += __shfl_xor(ss, 2);
        const float sc = 1.0f / (sqrtf(ss) + 1e-12f);
        v0.x*=sc; v0.y*=sc; v0.z*=sc; v0.w*=sc;
        v1.x*=sc; v1.y*=sc; v1.z*=sc; v1.w*=sc;
        *(float4*)(vw + r*36 + q*8)     = v0;
        *(float4*)(vw + r*36 + q*8 + 4) = v1;
        __syncthreads();
        {
            const float* va = vw + i1 * 36;
            const float* vb = vw + j1 * 36;
            float d = 0.f;
            #pragma unroll
            for (int c = 0; c < 8; ++c) {
                float4 a = *(const float4*)(va + c*4);
                float4 b = *(const float4*)(vb + c*4);
                d = fmaf(a.x, b.x, d); d = fmaf(a.y, b.y, d);
                d = fmaf(a.z, b.z, d); d = fmaf(a.w, b.w, d);
            }
            d = fminf(fmaxf(d, -1.0f + 1e-7f), 1.0f - 1e-7f);
            actA[m * ASTRIDE + l] = (f16)acosf(d);
        }
        if (has2) {
            const float* va = vw + i2 * 36;
            const float* vb = vw + j2 * 36;
            float d = 0.f;
            #pragma unroll
            for (int c = 0; c < 8; ++c) {
                float4 a = *(const float4*)(va + c*4);
                float4 b = *(const float4*)(vb + c*4);
                d = fmaf(a.x, b.x, d); d = fmaf(a.y, b.y, d);
                d = fmaf(a.z, b.z, d); d = fmaf(a.w, b.w, d);
            }
            d = fminf(fmaxf(d, -1.0f + 1e-7f), 1.0f - 1e-7f);
            actA[m * ASTRIDE + l + 64] = (f16)acosf(d);
        } else {
            actA[m * ASTRIDE + l + 64] = (f16)0.0f;  // zero-pad K 120..127
        }
    }
    __syncthreads();

    // ---------------- Phase B: MLP on MFMA ----------------
    const int lr = l & 15;
    const int lg = l >> 4;
    const int jg = w >> 1;   // 0..3
    const int ng = w & 1;    // 0..1

    mlp_layer_mfma(wt,             b1, actA, actB, jg, ng, lr, lg);
    __syncthreads();
    mlp_layer_mfma(wt + 16384,     b2, actB, actA, jg, ng, lr, lg);
    __syncthreads();
    mlp_layer_mfma(wt + 2 * 16384, b3, actA, actB, jg, ng, lr, lg);
    __syncthreads();

    // ---------------- final 128->1 + sigmoid: 8 threads per node ----------------
    {
        const int node = t >> 3;       // 0..63
        const int part = t & 7;        // 0..7
        const int i0 = part * 16;
        const f16* sr = actB + node * ASTRIDE + i0;
        f16x8 h0 = *(const f16x8*)(sr);
        f16x8 h1 = *(const f16x8*)(sr + 8);
        float s = 0.f;
        #pragma unroll
        for (int e = 0; e < 8; ++e) s = fmaf((float)h0[e], W4[i0 + e], s);
        #pragma unroll
        for (int e = 0; e < 8; ++e) s = fmaf((float)h1[e], W4[i0 + 8 + e], s);
        s += __shfl_xor(s, 1);
        s += __shfl_xor(s, 2);
        s += __shfl_xor(s, 4);
        if (part == 0) {
            const long g = (long)base + node;
            if (g < n_nodes)
                out[g] = 1.0f / (1.0f + __expf(-(s + b4[0])));
        }
    }
}

extern "C" void kernel_launch(void* const* d_in, const int* in_sizes, int n_in,
                              void* d_out, int out_size, void* d_ws, size_t ws_size,
                              hipStream_t stream) {
    // inputs: 0:x 1:edge_index 2:edge_attr 3:k 4:W1 5:b1 6:W2 7:b2 8:W3 9:b3 10:W4 11:b4
    const float* edge_attr = (const float*)d_in[2];
    const float* W1 = (const float*)d_in[4];
    const float* b1 = (const float*)d_in[5];
    const float* W2 = (const float*)d_in[6];
    const float* b2 = (const float*)d_in[7];
    const float* W3 = (const float*)d_in[8];
    const float* b3 = (const float*)d_in[9];
    const float* W4 = (const float*)d_in[10];
    const float* b4 = (const float*)d_in[11];
    float* out = (float*)d_out;
    f16* wt = (f16*)d_ws;                        // 3*128*128 f16 = 96 KB

    const int n_nodes = in_sizes[2] / 512;       // E*D / (16*32)

    prep_weights<<<(3 * 128 * 128 + 255) / 256, 256, 0, stream>>>(W1, W2, W3, wt);

    const int blocks = (n_nodes + CHUNK - 1) / CHUNK;
    gnn_angle_fused<<<blocks, NTHREADS, 0, stream>>>(
        edge_attr, wt, b1, b2, b3, W4, b4, out, n_nodes);
}

// Round 3
// 169.162 us; speedup vs baseline: 2.0909x; 1.0474x over previous
//
#include <hip/hip_runtime.h>
#include <hip/hip_bf16.h>
#include <math.h>

// GNNAngle: per node, 16 neighbor vectors (D=32) -> normalize -> 120 pairwise
// angles -> MLP 120->128->128->128->1 (tanh,tanh,tanh,sigmoid).
// Round 3: Gram matrix (cosines) on MFMA too. Per node: one wave loads the
// 16x32 block (lane l -> row l&15, dims (l>>4)*8..+8 == the A AND B fragment
// of vn*vn^T), normalizes in-register, one mfma_f32_16x16x32_f16 -> all 256
// cosines, 4 predicated acos + f16 scatter to LDS. No dot-product loops, no
// vecs LDS, no barriers inside phase A.

#define CHUNK     64    // nodes per block
#define NTHREADS  512   // 8 waves
#define ASTRIDE   136   // f16 act row stride (b128 conflict-free in MLP)

typedef _Float16 f16;
typedef f16  f16x8 __attribute__((ext_vector_type(8)));
typedef f16  f16x4 __attribute__((ext_vector_type(4)));
typedef float f32x4 __attribute__((ext_vector_type(4)));

__device__ __forceinline__ float fast_tanh(float x) {
    float e = __expf(2.0f * x);
    return 1.0f - 2.0f / (e + 1.0f);
}

// ---- prep: W[i][j] (f32, row-major [IN][128]) -> Wt[j][i] f16 [128][128], K zero-padded
__global__ void prep_weights(const float* __restrict__ W1,
                             const float* __restrict__ W2,
                             const float* __restrict__ W3,
                             f16* __restrict__ wt)
{
    int tid = blockIdx.x * 256 + threadIdx.x;
    if (tid >= 3 * 128 * 128) return;
    int layer = tid >> 14;
    int rem   = tid & 16383;
    int j     = rem >> 7;
    int i     = rem & 127;
    const float* W = (layer == 0) ? W1 : ((layer == 1) ? W2 : W3);
    int in_l = (layer == 0) ? 120 : 128;
    float v = (i < in_l) ? W[i * 128 + j] : 0.0f;
    wt[tid] = (f16)v;   // wt[layer][j][i]
}

// one MLP layer on MFMA: dst[node][j] = tanh(sum_i src[node][i]*W[i][j] + b[j])
__device__ __forceinline__ void mlp_layer_mfma(const f16* __restrict__ wl,   // [128][128] f16 ([j][i])
                                               const float* __restrict__ bias,
                                               const f16* src, f16* dst,     // LDS, stride ASTRIDE
                                               int jg, int ng, int lr, int lg)
{
    f16x8 a0[4], a1[4];
    f32x4 bv0, bv1;
    {
        const int jt0 = jg * 2, jt1 = jg * 2 + 1;
        const f16* wr0 = wl + (jt0 * 16 + lr) * 128 + lg * 8;
        const f16* wr1 = wl + (jt1 * 16 + lr) * 128 + lg * 8;
        #pragma unroll
        for (int kt = 0; kt < 4; ++kt) {
            a0[kt] = *(const f16x8*)(wr0 + kt * 32);
            a1[kt] = *(const f16x8*)(wr1 + kt * 32);
        }
        bv0 = *(const f32x4*)(bias + jt0 * 16 + lg * 4);
        bv1 = *(const f32x4*)(bias + jt1 * 16 + lg * 4);
    }
    #pragma unroll
    for (int nt2 = 0; nt2 < 2; ++nt2) {
        const int node = (ng * 2 + nt2) * 16 + lr;
        const f16* sr = src + node * ASTRIDE + lg * 8;
        f16x8 bf0 = *(const f16x8*)(sr);
        f16x8 bf1 = *(const f16x8*)(sr + 32);
        f16x8 bf2 = *(const f16x8*)(sr + 64);
        f16x8 bf3 = *(const f16x8*)(sr + 96);
        f32x4 acc0 = {0.f, 0.f, 0.f, 0.f};
        f32x4 acc1 = {0.f, 0.f, 0.f, 0.f};
        acc0 = __builtin_amdgcn_mfma_f32_16x16x32_f16(a0[0], bf0, acc0, 0, 0, 0);
        acc1 = __builtin_amdgcn_mfma_f32_16x16x32_f16(a1[0], bf0, acc1, 0, 0, 0);
        acc0 = __builtin_amdgcn_mfma_f32_16x16x32_f16(a0[1], bf1, acc0, 0, 0, 0);
        acc1 = __builtin_amdgcn_mfma_f32_16x16x32_f16(a1[1], bf1, acc1, 0, 0, 0);
        acc0 = __builtin_amdgcn_mfma_f32_16x16x32_f16(a0[2], bf2, acc0, 0, 0, 0);
        acc1 = __builtin_amdgcn_mfma_f32_16x16x32_f16(a1[2], bf2, acc1, 0, 0, 0);
        acc0 = __builtin_amdgcn_mfma_f32_16x16x32_f16(a0[3], bf3, acc0, 0, 0, 0);
        acc1 = __builtin_amdgcn_mfma_f32_16x16x32_f16(a1[3], bf3, acc1, 0, 0, 0);
        // D[row=j_local=lg*4+r][col=node=lr]; bias+tanh -> f16 -> LDS
        f16x4 o0, o1;
        #pragma unroll
        for (int r = 0; r < 4; ++r) {
            o0[r] = (f16)fast_tanh(acc0[r] + bv0[r]);
            o1[r] = (f16)fast_tanh(acc1[r] + bv1[r]);
        }
        *(f16x4*)(dst + node * ASTRIDE + (jg * 2 + 0) * 16 + lg * 4) = o0;
        *(f16x4*)(dst + node * ASTRIDE + (jg * 2 + 1) * 16 + lg * 4) = o1;
    }
}

__global__ __launch_bounds__(NTHREADS, 4)
void gnn_angle_fused(const float* __restrict__ edge_attr,
                     const f16*   __restrict__ wt,     // 3x[128][128] f16
                     const float* __restrict__ b1, const float* __restrict__ b2,
                     const float* __restrict__ b3,
                     const float* __restrict__ W4, const float* __restrict__ b4,
                     float* __restrict__ out, int n_nodes)
{
    __shared__ __attribute__((aligned(16))) f16 actA[CHUNK * ASTRIDE];
    __shared__ __attribute__((aligned(16))) f16 actB[CHUNK * ASTRIDE];

    const int t = threadIdx.x;
    const int w = t >> 6;
    const int l = t & 63;
    const int base = blockIdx.x * CHUNK;
    const int lr = l & 15;
    const int lg = l >> 4;

    // ---------------- Phase A: normalize + Gram via MFMA + acos ----------------
    for (int it = 0; it < 8; ++it) {
        const int m = it * 8 + w;                // local node 0..63
        const long g = (long)base + m;
        const bool valid = (g < n_nodes);
        float4 v0 = make_float4(0.f, 0.f, 0.f, 0.f);
        float4 v1 = v0;
        if (valid) {
            const float* src = edge_attr + g * 512 + lr * 32 + lg * 8;
            v0 = *(const float4*)(src);
            v1 = *(const float4*)(src + 4);
        }
        float ss = v0.x*v0.x + v0.y*v0.y + v0.z*v0.z + v0.w*v0.w
                 + v1.x*v1.x + v1.y*v1.y + v1.z*v1.z + v1.w*v1.w;
        ss += __shfl_xor(ss, 16);
        ss += __shfl_xor(ss, 32);                // row (lr) norm across lg lanes
        const float sc = 1.0f / (sqrtf(ss) + 1e-12f);
        f16x8 frag;
        frag[0] = (f16)(v0.x * sc); frag[1] = (f16)(v0.y * sc);
        frag[2] = (f16)(v0.z * sc); frag[3] = (f16)(v0.w * sc);
        frag[4] = (f16)(v1.x * sc); frag[5] = (f16)(v1.y * sc);
        frag[6] = (f16)(v1.z * sc); frag[7] = (f16)(v1.w * sc);
        f32x4 acc = {0.f, 0.f, 0.f, 0.f};
        acc = __builtin_amdgcn_mfma_f32_16x16x32_f16(frag, frag, acc, 0, 0, 0);
        // zero-pad feats 120..127 (K padding for layer 1)
        if (l < 8) actA[m * ASTRIDE + 120 + l] = (f16)0.f;
        // upper triangle: lane holds cos for col=lr, rows lg*4+r
        const int col = lr;
        #pragma unroll
        for (int r2 = 0; r2 < 4; ++r2) {
            const int row = lg * 4 + r2;
            if (row < col) {
                float c = fminf(fmaxf(acc[r2], -1.0f + 1e-7f), 1.0f - 1e-7f);
                const int p = 15 * row - ((row * (row - 1)) >> 1) + (col - row - 1);
                actA[m * ASTRIDE + p] = (f16)acosf(c);
            }
        }
    }
    __syncthreads();

    // ---------------- Phase B: MLP on MFMA ----------------
    const int jg = w >> 1;   // 0..3
    const int ng = w & 1;    // 0..1

    mlp_layer_mfma(wt,             b1, actA, actB, jg, ng, lr, lg);
    __syncthreads();
    mlp_layer_mfma(wt + 16384,     b2, actB, actA, jg, ng, lr, lg);
    __syncthreads();
    mlp_layer_mfma(wt + 2 * 16384, b3, actA, actB, jg, ng, lr, lg);
    __syncthreads();

    // ---------------- final 128->1 + sigmoid: 8 threads per node ----------------
    {
        const int node = t >> 3;       // 0..63
        const int part = t & 7;        // 0..7
        const int i0 = part * 16;
        const f16* sr = actB + node * ASTRIDE + i0;
        f16x8 h0 = *(const f16x8*)(sr);
        f16x8 h1 = *(const f16x8*)(sr + 8);
        float s = 0.f;
        #pragma unroll
        for (int e = 0; e < 8; ++e) s = fmaf((float)h0[e], W4[i0 + e], s);
        #pragma unroll
        for (int e = 0; e < 8; ++e) s = fmaf((float)h1[e], W4[i0 + 8 + e], s);
        s += __shfl_xor(s, 1);
        s += __shfl_xor(s, 2);
        s += __shfl_xor(s, 4);
        if (part == 0) {
            const long g = (long)base + node;
            if (g < n_nodes)
                out[g] = 1.0f / (1.0f + __expf(-(s + b4[0])));
        }
    }
}

extern "C" void kernel_launch(void* const* d_in, const int* in_sizes, int n_in,
                              void* d_out, int out_size, void* d_ws, size_t ws_size,
                              hipStream_t stream) {
    // inputs: 0:x 1:edge_index 2:edge_attr 3:k 4:W1 5:b1 6:W2 7:b2 8:W3 9:b3 10:W4 11:b4
    const float* edge_attr = (const float*)d_in[2];
    const float* W1 = (const float*)d_in[4];
    const float* b1 = (const float*)d_in[5];
    const float* W2 = (const float*)d_in[6];
    const float* b2 = (const float*)d_in[7];
    const float* W3 = (const float*)d_in[8];
    const float* b3 = (const float*)d_in[9];
    const float* W4 = (const float*)d_in[10];
    const float* b4 = (const float*)d_in[11];
    float* out = (float*)d_out;
    f16* wt = (f16*)d_ws;                        // 3*128*128 f16 = 96 KB

    const int n_nodes = in_sizes[2] / 512;       // E*D / (16*32)

    prep_weights<<<(3 * 128 * 128 + 255) / 256, 256, 0, stream>>>(W1, W2, W3, wt);

    const int blocks = (n_nodes + CHUNK - 1) / CHUNK;
    gnn_angle_fused<<<blocks, NTHREADS, 0, stream>>>(
        edge_attr, wt, b1, b2, b3, W4, b4, out, n_nodes);
}

// Round 4
// 152.238 us; speedup vs baseline: 2.3234x; 1.1112x over previous
//
#include <hip/hip_runtime.h>
#include <hip/hip_bf16.h>
#include <math.h>

// GNNAngle: per node, 16 neighbor vectors (D=32) -> normalize -> 120 pairwise
// angles -> MLP 120->128->128->128->1 (tanh,tanh,tanh,sigmoid).
// Round 4: fast polynomial acos (A&S 4.4.45, 6.7e-5 rad), 2-deep prefetch of
// phase-A global loads, v_rsq/v_rcp for norm/tanh/sigmoid. Gram + MLP on
// f16 MFMA as in round 3.

#define CHUNK     64    // nodes per block
#define NTHREADS  512   // 8 waves
#define ASTRIDE   136   // f16 act row stride (b128 conflict-free in MLP)

typedef _Float16 f16;
typedef f16  f16x8 __attribute__((ext_vector_type(8)));
typedef f16  f16x4 __attribute__((ext_vector_type(4)));
typedef float f32x4 __attribute__((ext_vector_type(4)));

__device__ __forceinline__ float fast_tanh(float x) {
    // tanh(x) = 1 - 2/(exp(2x)+1); v_exp + v_rcp, ~1e-6 abs error
    float e = __expf(2.0f * x);
    return 1.0f - 2.0f * __builtin_amdgcn_rcpf(e + 1.0f);
}

__device__ __forceinline__ float fast_acos(float x) {
    // Abramowitz-Stegun 4.4.45: max abs error 6.7e-5 rad, branchless
    float ax = fabsf(x);
    float p = fmaf(-0.0187293f, ax, 0.0742610f);
    p = fmaf(p, ax, -0.2121144f);
    p = fmaf(p, ax, 1.5707288f);
    float r = sqrtf(1.0f - ax) * p;          // acos(|x|)
    return (x >= 0.0f) ? r : (3.14159265358979f - r);
}

// ---- prep: W[i][j] (f32, row-major [IN][128]) -> Wt[j][i] f16 [128][128], K zero-padded
__global__ void prep_weights(const float* __restrict__ W1,
                             const float* __restrict__ W2,
                             const float* __restrict__ W3,
                             f16* __restrict__ wt)
{
    int tid = blockIdx.x * 256 + threadIdx.x;
    if (tid >= 3 * 128 * 128) return;
    int layer = tid >> 14;
    int rem   = tid & 16383;
    int j     = rem >> 7;
    int i     = rem & 127;
    const float* W = (layer == 0) ? W1 : ((layer == 1) ? W2 : W3);
    int in_l = (layer == 0) ? 120 : 128;
    float v = (i < in_l) ? W[i * 128 + j] : 0.0f;
    wt[tid] = (f16)v;   // wt[layer][j][i]
}

// one MLP layer on MFMA: dst[node][j] = tanh(sum_i src[node][i]*W[i][j] + b[j])
__device__ __forceinline__ void mlp_layer_mfma(const f16* __restrict__ wl,   // [128][128] f16 ([j][i])
                                               const float* __restrict__ bias,
                                               const f16* src, f16* dst,     // LDS, stride ASTRIDE
                                               int jg, int ng, int lr, int lg)
{
    f16x8 a0[4], a1[4];
    f32x4 bv0, bv1;
    {
        const int jt0 = jg * 2, jt1 = jg * 2 + 1;
        const f16* wr0 = wl + (jt0 * 16 + lr) * 128 + lg * 8;
        const f16* wr1 = wl + (jt1 * 16 + lr) * 128 + lg * 8;
        #pragma unroll
        for (int kt = 0; kt < 4; ++kt) {
            a0[kt] = *(const f16x8*)(wr0 + kt * 32);
            a1[kt] = *(const f16x8*)(wr1 + kt * 32);
        }
        bv0 = *(const f32x4*)(bias + jt0 * 16 + lg * 4);
        bv1 = *(const f32x4*)(bias + jt1 * 16 + lg * 4);
    }
    #pragma unroll
    for (int nt2 = 0; nt2 < 2; ++nt2) {
        const int node = (ng * 2 + nt2) * 16 + lr;
        const f16* sr = src + node * ASTRIDE + lg * 8;
        f16x8 bf0 = *(const f16x8*)(sr);
        f16x8 bf1 = *(const f16x8*)(sr + 32);
        f16x8 bf2 = *(const f16x8*)(sr + 64);
        f16x8 bf3 = *(const f16x8*)(sr + 96);
        f32x4 acc0 = {0.f, 0.f, 0.f, 0.f};
        f32x4 acc1 = {0.f, 0.f, 0.f, 0.f};
        acc0 = __builtin_amdgcn_mfma_f32_16x16x32_f16(a0[0], bf0, acc0, 0, 0, 0);
        acc1 = __builtin_amdgcn_mfma_f32_16x16x32_f16(a1[0], bf0, acc1, 0, 0, 0);
        acc0 = __builtin_amdgcn_mfma_f32_16x16x32_f16(a0[1], bf1, acc0, 0, 0, 0);
        acc1 = __builtin_amdgcn_mfma_f32_16x16x32_f16(a1[1], bf1, acc1, 0, 0, 0);
        acc0 = __builtin_amdgcn_mfma_f32_16x16x32_f16(a0[2], bf2, acc0, 0, 0, 0);
        acc1 = __builtin_amdgcn_mfma_f32_16x16x32_f16(a1[2], bf2, acc1, 0, 0, 0);
        acc0 = __builtin_amdgcn_mfma_f32_16x16x32_f16(a0[3], bf3, acc0, 0, 0, 0);
        acc1 = __builtin_amdgcn_mfma_f32_16x16x32_f16(a1[3], bf3, acc1, 0, 0, 0);
        // D[row=j_local=lg*4+r][col=node=lr]; bias+tanh -> f16 -> LDS
        f16x4 o0, o1;
        #pragma unroll
        for (int r = 0; r < 4; ++r) {
            o0[r] = (f16)fast_tanh(acc0[r] + bv0[r]);
            o1[r] = (f16)fast_tanh(acc1[r] + bv1[r]);
        }
        *(f16x4*)(dst + node * ASTRIDE + (jg * 2 + 0) * 16 + lg * 4) = o0;
        *(f16x4*)(dst + node * ASTRIDE + (jg * 2 + 1) * 16 + lg * 4) = o1;
    }
}

__global__ __launch_bounds__(NTHREADS, 4)
void gnn_angle_fused(const float* __restrict__ edge_attr,
                     const f16*   __restrict__ wt,     // 3x[128][128] f16
                     const float* __restrict__ b1, const float* __restrict__ b2,
                     const float* __restrict__ b3,
                     const float* __restrict__ W4, const float* __restrict__ b4,
                     float* __restrict__ out, int n_nodes)
{
    __shared__ __attribute__((aligned(16))) f16 actA[CHUNK * ASTRIDE];
    __shared__ __attribute__((aligned(16))) f16 actB[CHUNK * ASTRIDE];

    const int t = threadIdx.x;
    const int w = t >> 6;
    const int l = t & 63;
    const int base = blockIdx.x * CHUNK;
    const int lr = l & 15;
    const int lg = l >> 4;

    // ---------------- Phase A: normalize + Gram via MFMA + acos ----------------
    // 2-deep pipeline: iteration it+1's global loads issue before it's compute.
    const float* srcw = edge_attr + (long)(base + w) * 512 + lr * 32 + lg * 8;
    float4 c0 = make_float4(0.f, 0.f, 0.f, 0.f), c1 = c0;
    if ((long)base + w < n_nodes) {
        c0 = *(const float4*)(srcw);
        c1 = *(const float4*)(srcw + 4);
    }
    for (int it = 0; it < 8; ++it) {
        const int m = it * 8 + w;                // local node 0..63
        float4 n0 = make_float4(0.f, 0.f, 0.f, 0.f), n1 = n0;
        if (it < 7 && (long)base + m + 8 < n_nodes) {
            const float* s = srcw + (it + 1) * 8 * 512;
            n0 = *(const float4*)(s);
            n1 = *(const float4*)(s + 4);
        }
        float ss = c0.x*c0.x + c0.y*c0.y + c0.z*c0.z + c0.w*c0.w
                 + c1.x*c1.x + c1.y*c1.y + c1.z*c1.z + c1.w*c1.w;
        ss += __shfl_xor(ss, 16);
        ss += __shfl_xor(ss, 32);                // row (lr) norm across lg lanes
        const float sc = __builtin_amdgcn_rsqf(ss + 1e-24f);
        f16x8 frag;
        frag[0] = (f16)(c0.x * sc); frag[1] = (f16)(c0.y * sc);
        frag[2] = (f16)(c0.z * sc); frag[3] = (f16)(c0.w * sc);
        frag[4] = (f16)(c1.x * sc); frag[5] = (f16)(c1.y * sc);
        frag[6] = (f16)(c1.z * sc); frag[7] = (f16)(c1.w * sc);
        f32x4 acc = {0.f, 0.f, 0.f, 0.f};
        acc = __builtin_amdgcn_mfma_f32_16x16x32_f16(frag, frag, acc, 0, 0, 0);
        // zero-pad feats 120..127 (K padding for layer 1)
        if (l < 8) actA[m * ASTRIDE + 120 + l] = (f16)0.f;
        // upper triangle: lane holds cos for col=lr, rows lg*4+r
        const int col = lr;
        #pragma unroll
        for (int r2 = 0; r2 < 4; ++r2) {
            const int row = lg * 4 + r2;
            float c = fminf(fmaxf(acc[r2], -1.0f + 1e-7f), 1.0f - 1e-7f);
            float ang = fast_acos(c);            // branchless, unconditional
            if (row < col) {
                const int p = 15 * row - ((row * (row - 1)) >> 1) + (col - row - 1);
                actA[m * ASTRIDE + p] = (f16)ang;
            }
        }
        c0 = n0; c1 = n1;
    }
    __syncthreads();

    // ---------------- Phase B: MLP on MFMA ----------------
    const int jg = w >> 1;   // 0..3
    const int ng = w & 1;    // 0..1

    mlp_layer_mfma(wt,             b1, actA, actB, jg, ng, lr, lg);
    __syncthreads();
    mlp_layer_mfma(wt + 16384,     b2, actB, actA, jg, ng, lr, lg);
    __syncthreads();
    mlp_layer_mfma(wt + 2 * 16384, b3, actA, actB, jg, ng, lr, lg);
    __syncthreads();

    // ---------------- final 128->1 + sigmoid: 8 threads per node ----------------
    {
        const int node = t >> 3;       // 0..63
        const int part = t & 7;        // 0..7
        const int i0 = part * 16;
        const f16* sr = actB + node * ASTRIDE + i0;
        f16x8 h0 = *(const f16x8*)(sr);
        f16x8 h1 = *(const f16x8*)(sr + 8);
        float s = 0.f;
        #pragma unroll
        for (int e = 0; e < 8; ++e) s = fmaf((float)h0[e], W4[i0 + e], s);
        #pragma unroll
        for (int e = 0; e < 8; ++e) s = fmaf((float)h1[e], W4[i0 + 8 + e], s);
        s += __shfl_xor(s, 1);
        s += __shfl_xor(s, 2);
        s += __shfl_xor(s, 4);
        if (part == 0) {
            const long g = (long)base + node;
            if (g < n_nodes)
                out[g] = __builtin_amdgcn_rcpf(1.0f + __expf(-(s + b4[0])));
        }
    }
}

extern "C" void kernel_launch(void* const* d_in, const int* in_sizes, int n_in,
                              void* d_out, int out_size, void* d_ws, size_t ws_size,
                              hipStream_t stream) {
    // inputs: 0:x 1:edge_index 2:edge_attr 3:k 4:W1 5:b1 6:W2 7:b2 8:W3 9:b3 10:W4 11:b4
    const float* edge_attr = (const float*)d_in[2];
    const float* W1 = (const float*)d_in[4];
    const float* b1 = (const float*)d_in[5];
    const float* W2 = (const float*)d_in[6];
    const float* b2 = (const float*)d_in[7];
    const float* W3 = (const float*)d_in[8];
    const float* b3 = (const float*)d_in[9];
    const float* W4 = (const float*)d_in[10];
    const float* b4 = (const float*)d_in[11];
    float* out = (float*)d_out;
    f16* wt = (f16*)d_ws;                        // 3*128*128 f16 = 96 KB

    const int n_nodes = in_sizes[2] / 512;       // E*D / (16*32)

    prep_weights<<<(3 * 128 * 128 + 255) / 256, 256, 0, stream>>>(W1, W2, W3, wt);

    const int blocks = (n_nodes + CHUNK - 1) / CHUNK;
    gnn_angle_fused<<<blocks, NTHREADS, 0, stream>>>(
        edge_attr, wt, b1, b2, b3, W4, b4, out, n_nodes);
}